// Round 1
// baseline (1057.948 us; speedup 1.0000x reference)
//
#include <hip/hip_runtime.h>
#include <math.h>

typedef unsigned short u16;
typedef __attribute__((ext_vector_type(8))) short bf16x8;
typedef __attribute__((ext_vector_type(4))) float f32x4;

#define S_N 16384
#define Q_N 4096
#define D_N 1024
#define C_N 256
#define NS 4
#define BQ 64
#define BS 128
#define BK 64
#define SRANGE (S_N / NS)     // 4096
#define NTILES (SRANGE / BS)  // 32
#define NKC (D_N / BK)        // 16

// ---- workspace layout (bytes) ----
#define WS_MASSP   0u                         // NS*Q*C*4 = 16,777,216
#define WS_MU      16777216u                  // D*4
#define WS_COUNTS  (WS_MU + 4096u)            // C*4 (int)
#define WS_NORMS   (WS_COUNTS + 1024u)        // S*4
#define WS_COLPART (WS_NORMS + 65536u)        // 64*D*4 = 262,144
#define WS_SUPPB   (WS_COLPART + 262144u)     // S*D*2 = 33,554,432
#define WS_QB      (WS_SUPPB + 33554432u)     // Q*D*2 = 8,388,608

__device__ __forceinline__ u16 f2bf(float f) {
    unsigned x = __float_as_uint(f);
    return (u16)((x + 0x7fffu + ((x >> 16) & 1u)) >> 16);
}

__device__ __forceinline__ float blkSum(float v, float* sh) {
#pragma unroll
    for (int o = 32; o; o >>= 1) v += __shfl_down(v, o);
    if ((threadIdx.x & 63) == 0) sh[threadIdx.x >> 6] = v;
    __syncthreads();
    float r = sh[0] + sh[1] + sh[2] + sh[3];
    __syncthreads();
    return r;
}

__device__ __forceinline__ float blkMax(float v, float* sh) {
#pragma unroll
    for (int o = 32; o; o >>= 1) v = fmaxf(v, __shfl_down(v, o));
    if ((threadIdx.x & 63) == 0) sh[threadIdx.x >> 6] = v;
    __syncthreads();
    float r = fmaxf(fmaxf(sh[0], sh[1]), fmaxf(sh[2], sh[3]));
    __syncthreads();
    return r;
}

// ---- row L2 norms of raw support (wave per row) ----
__global__ void k_norms(const float* __restrict__ sup, float* __restrict__ norms) {
    int lane = threadIdx.x & 63, w = threadIdx.x >> 6;
    int row = blockIdx.x * 4 + w;
    const float4* rp = (const float4*)(sup + (size_t)row * D_N);
    float ss = 0.f;
#pragma unroll
    for (int i = 0; i < 4; i++) {
        float4 v = rp[lane + 64 * i];
        ss += v.x * v.x + v.y * v.y + v.z * v.z + v.w * v.w;
    }
#pragma unroll
    for (int o = 32; o; o >>= 1) ss += __shfl_down(ss, o);
    if (lane == 0) norms[row] = sqrtf(ss);
}

// ---- partial column sums of normalized support ----
__global__ void k_colpart(const float* __restrict__ sup, const float* __restrict__ norms,
                          float* __restrict__ colpart) {
    int rc = blockIdx.x >> 2, cg = blockIdx.x & 3;
    int c = cg * 256 + threadIdx.x;
    int r0 = rc * 256;
    float acc = 0.f;
    for (int i = 0; i < 256; i++) {
        int r = r0 + i;
        float inv = 1.f / fmaxf(norms[r], 1e-8f);
        acc += sup[(size_t)r * D_N + c] * inv;
    }
    colpart[rc * D_N + c] = acc;
}

// ---- reduce partials -> mu ----
__global__ void k_mu(const float* __restrict__ colpart, float* __restrict__ mu) {
    int c = blockIdx.x * 256 + threadIdx.x;
    float s = 0.f;
#pragma unroll 8
    for (int i = 0; i < 64; i++) s += colpart[i * D_N + c];
    mu[c] = s * (1.f / (float)S_N);
}

// ---- support: normalize, center, renormalize, -> bf16 ----
__global__ void k_suptrans(const float* __restrict__ sup, const float* __restrict__ norms,
                           const float* __restrict__ mu, u16* __restrict__ outb) {
    __shared__ float sh[4];
    int r = blockIdx.x, t = threadIdx.x;
    float inv = 1.f / fmaxf(norms[r], 1e-8f);
    float4 x = ((const float4*)(sup + (size_t)r * D_N))[t];
    float4 m = ((const float4*)mu)[t];
    float4 y;
    y.x = x.x * inv - m.x; y.y = x.y * inv - m.y;
    y.z = x.z * inv - m.z; y.w = x.w * inv - m.w;
    float ss = y.x * y.x + y.y * y.y + y.z * y.z + y.w * y.w;
    float tot = blkSum(ss, sh);
    float inv2 = 1.f / fmaxf(sqrtf(tot), 1e-8f);
    ushort4 u;
    u.x = f2bf(y.x * inv2); u.y = f2bf(y.y * inv2);
    u.z = f2bf(y.z * inv2); u.w = f2bf(y.w * inv2);
    ((ushort4*)(outb + (size_t)r * D_N))[t] = u;
}

// ---- query: normalize, center, renormalize, -> bf16 ----
__global__ void k_qtrans(const float* __restrict__ qry, const float* __restrict__ mu,
                         u16* __restrict__ outb) {
    __shared__ float sh[4];
    int r = blockIdx.x, t = threadIdx.x;
    float4 x = ((const float4*)(qry + (size_t)r * D_N))[t];
    float ss1 = x.x * x.x + x.y * x.y + x.z * x.z + x.w * x.w;
    float tot1 = blkSum(ss1, sh);
    float inv1 = 1.f / fmaxf(sqrtf(tot1), 1e-8f);
    float4 m = ((const float4*)mu)[t];
    float4 y;
    y.x = x.x * inv1 - m.x; y.y = x.y * inv1 - m.y;
    y.z = x.z * inv1 - m.z; y.w = x.w * inv1 - m.w;
    float ss2 = y.x * y.x + y.y * y.y + y.z * y.z + y.w * y.w;
    float tot2 = blkSum(ss2, sh);
    float inv2 = 1.f / fmaxf(sqrtf(tot2), 1e-8f);
    ushort4 u;
    u.x = f2bf(y.x * inv2); u.y = f2bf(y.y * inv2);
    u.z = f2bf(y.z * inv2); u.w = f2bf(y.w * inv2);
    ((ushort4*)(outb + (size_t)r * D_N))[t] = u;
}

// ---- label histogram (int atomics) ----
__global__ void k_counts(const int* __restrict__ lab, int* __restrict__ counts) {
    int i = blockIdx.x * 256 + threadIdx.x;
    if (i < S_N) atomicAdd(&counts[lab[i]], 1);
}

// ---- main: exp(scale * Qb @ Sb^T) scattered by label into per-block class mass ----
__launch_bounds__(256, 1)
__global__ void k_mass(const u16* __restrict__ Qb, const u16* __restrict__ Sb,
                       const int* __restrict__ lab, const float* __restrict__ scale_p,
                       float* __restrict__ massp) {
    __shared__ float smass[BQ][C_N + 1];   // stride 257 decorrelates scatter banks
    __shared__ u16 sQ[BQ * BK];
    __shared__ u16 sS[BS * BK];
    __shared__ int slab[BS];

    const int t = threadIdx.x;
    const int lane = t & 63;
    const int wid = t >> 6;
    const int wrow = wid >> 1, wcol = wid & 1;
    const int qblk = blockIdx.x & 63;
    const int sblk = blockIdx.x >> 6;
    const int qbase = qblk * BQ;
    const int s0 = sblk * SRANGE;
    const int l15 = lane & 15, l4 = lane >> 4;

    for (int i = t; i < BQ * (C_N + 1); i += 256) (&smass[0][0])[i] = 0.f;

    const float scale = fminf(fmaxf(*scale_p, 1.f), 20.f);

    // staging geometry: thread t handles 16B chunk (row srow + 32k, chunk sck)
    const int srow = t >> 3;   // 0..31
    const int sck = t & 7;     // 0..7
    const int wb = (srow * 128 + sck * 16) ^ ((srow & 7) << 4);  // swizzled LDS byte off

    // fragment read byte offsets (same swizzle)
    int aoff[2][2], boff[4][2];
#pragma unroll
    for (int m = 0; m < 2; m++)
#pragma unroll
        for (int k2 = 0; k2 < 2; k2++) {
            int r = wrow * 32 + m * 16 + l15;
            aoff[m][k2] = (r * 128 + k2 * 64 + l4 * 16) ^ ((r & 7) << 4);
        }
#pragma unroll
    for (int n = 0; n < 4; n++)
#pragma unroll
        for (int k2 = 0; k2 < 2; k2++) {
            int r = wcol * 64 + n * 16 + l15;
            boff[n][k2] = (r * 128 + k2 * 64 + l4 * 16) ^ ((r & 7) << 4);
        }

    uint4 rq[2], rs[4];
    auto loadQ = [&](int kc) {
        const u16* p = Qb + (size_t)(qbase + srow) * D_N + kc * BK + sck * 8;
        rq[0] = *(const uint4*)p;
        rq[1] = *(const uint4*)(p + 32 * D_N);
    };
    auto loadS = [&](int sbase, int kc) {
        const u16* p = Sb + (size_t)(sbase + srow) * D_N + kc * BK + sck * 8;
        rs[0] = *(const uint4*)p;
        rs[1] = *(const uint4*)(p + 32 * D_N);
        rs[2] = *(const uint4*)(p + 64 * D_N);
        rs[3] = *(const uint4*)(p + 96 * D_N);
    };

    loadQ(0);
    loadS(s0, 0);

    for (int st = 0; st < NTILES; ++st) {
        int sbase = s0 + st * BS;
        f32x4 acc[2][4];
#pragma unroll
        for (int m = 0; m < 2; m++)
#pragma unroll
            for (int n = 0; n < 4; n++) acc[m][n] = (f32x4){0.f, 0.f, 0.f, 0.f};

        for (int kc = 0; kc < NKC; ++kc) {
            __syncthreads();  // prior reads (MFMA / scatter-slab) done
            *(uint4*)((char*)sQ + wb) = rq[0];
            *(uint4*)((char*)sQ + wb + 4096) = rq[1];
#pragma unroll
            for (int i = 0; i < 4; i++) *(uint4*)((char*)sS + wb + i * 4096) = rs[i];
            if (kc == 0 && t < BS) slab[t] = lab[sbase + t];
            __syncthreads();

            // T14: issue next chunk's global loads; latency hides under MFMA
            int nkc, nsb;
            if (kc < NKC - 1) { nkc = kc + 1; nsb = sbase; }
            else { nkc = 0; nsb = (st + 1 < NTILES) ? sbase + BS : sbase; }
            loadQ(nkc);
            loadS(nsb, nkc);

#pragma unroll
            for (int k2 = 0; k2 < 2; k2++) {
                bf16x8 a0 = *(const bf16x8*)((const char*)sQ + aoff[0][k2]);
                bf16x8 a1 = *(const bf16x8*)((const char*)sQ + aoff[1][k2]);
                bf16x8 b0 = *(const bf16x8*)((const char*)sS + boff[0][k2]);
                bf16x8 b1 = *(const bf16x8*)((const char*)sS + boff[1][k2]);
                bf16x8 b2 = *(const bf16x8*)((const char*)sS + boff[2][k2]);
                bf16x8 b3 = *(const bf16x8*)((const char*)sS + boff[3][k2]);
                acc[0][0] = __builtin_amdgcn_mfma_f32_16x16x32_bf16(a0, b0, acc[0][0], 0, 0, 0);
                acc[0][1] = __builtin_amdgcn_mfma_f32_16x16x32_bf16(a0, b1, acc[0][1], 0, 0, 0);
                acc[0][2] = __builtin_amdgcn_mfma_f32_16x16x32_bf16(a0, b2, acc[0][2], 0, 0, 0);
                acc[0][3] = __builtin_amdgcn_mfma_f32_16x16x32_bf16(a0, b3, acc[0][3], 0, 0, 0);
                acc[1][0] = __builtin_amdgcn_mfma_f32_16x16x32_bf16(a1, b0, acc[1][0], 0, 0, 0);
                acc[1][1] = __builtin_amdgcn_mfma_f32_16x16x32_bf16(a1, b1, acc[1][1], 0, 0, 0);
                acc[1][2] = __builtin_amdgcn_mfma_f32_16x16x32_bf16(a1, b2, acc[1][2], 0, 0, 0);
                acc[1][3] = __builtin_amdgcn_mfma_f32_16x16x32_bf16(a1, b3, acc[1][3], 0, 0, 0);
            }
        }

        // exp + scatter by label into LDS mass (C/D layout: row=(l>>4)*4+reg, col=l&15)
#pragma unroll
        for (int m = 0; m < 2; m++)
#pragma unroll
            for (int n = 0; n < 4; n++) {
                int sc = wcol * 64 + n * 16 + l15;
                int c = slab[sc];
                int qr = wrow * 32 + m * 16 + l4 * 4;
#pragma unroll
                for (int r4 = 0; r4 < 4; r4++) {
                    float v = __expf(acc[m][n][r4] * scale);
                    atomicAdd(&smass[qr + r4][c], v);
                }
            }
    }
    __syncthreads();

    float* mp = massp + (size_t)sblk * Q_N * C_N + (size_t)qbase * C_N;
    for (int i = t; i < BQ * C_N; i += 256) {
        int r = i >> 8, c = i & 255;
        mp[r * C_N + c] = smass[r][c];
    }
}

// ---- finalize: normalize mass, log, prior, softmax, write all outputs ----
__global__ void k_final(const float* __restrict__ massp, const int* __restrict__ counts,
                        const float* __restrict__ cp_p, float* __restrict__ out) {
    __shared__ float sh[4];
    int q = blockIdx.x, c = threadIdx.x;
    float m = 0.f;
#pragma unroll
    for (int j = 0; j < NS; j++) m += massp[((size_t)j * Q_N + q) * C_N + c];
    float denom = blkSum(m, sh);
    float cp = *cp_p;
    float logit = logf(fmaxf(m / denom, 1e-8f)) + cp * logf(fmaxf((float)counts[c], 1.f));
    float mx = blkMax(logit, sh);
    float e = __expf(logit - mx);
    float se = blkSum(e, sh);
    out[(size_t)q * C_N + c] = logit;
    out[(size_t)Q_N * C_N + C_N + (size_t)q * C_N + c] = e / se;
    if (q == 0) out[(size_t)Q_N * C_N + c] = (float)c;
}

extern "C" void kernel_launch(void* const* d_in, const int* in_sizes, int n_in,
                              void* d_out, int out_size, void* d_ws, size_t ws_size,
                              hipStream_t stream) {
    const float* sup = (const float*)d_in[0];
    const int* lab = (const int*)d_in[1];
    const float* qry = (const float*)d_in[2];
    const float* ls = (const float*)d_in[3];
    const float* cp = (const float*)d_in[4];
    float* out = (float*)d_out;
    char* ws = (char*)d_ws;

    float* massp = (float*)(ws + WS_MASSP);
    float* mu = (float*)(ws + WS_MU);
    int* counts = (int*)(ws + WS_COUNTS);
    float* norms = (float*)(ws + WS_NORMS);
    float* colpart = (float*)(ws + WS_COLPART);
    u16* suppb = (u16*)(ws + WS_SUPPB);
    u16* qb = (u16*)(ws + WS_QB);

    hipMemsetAsync(counts, 0, C_N * sizeof(int), stream);
    k_norms<<<S_N / 4, 256, 0, stream>>>(sup, norms);
    k_colpart<<<256, 256, 0, stream>>>(sup, norms, colpart);
    k_mu<<<D_N / 256, 256, 0, stream>>>(colpart, mu);
    k_suptrans<<<S_N, 256, 0, stream>>>(sup, norms, mu, suppb);
    k_qtrans<<<Q_N, 256, 0, stream>>>(qry, mu, qb);
    k_counts<<<S_N / 256, 256, 0, stream>>>(lab, counts);
    k_mass<<<(Q_N / BQ) * NS, 256, 0, stream>>>(qb, suppb, lab, ls, massp);
    k_final<<<Q_N, 256, 0, stream>>>(massp, counts, cp, out);
}

// Round 2
// 833.984 us; speedup vs baseline: 1.2685x; 1.2685x over previous
//
#include <hip/hip_runtime.h>
#include <math.h>

typedef unsigned short u16;
typedef __attribute__((ext_vector_type(8))) short bf16x8;
typedef __attribute__((ext_vector_type(4))) float f32x4;

#define S_N 16384
#define Q_N 4096
#define D_N 1024
#define C_N 256
#define NS 16
#define BQ 128
#define BS 128
#define BK 64
#define SRANGE (S_N / NS)     // 1024
#define NTILES (SRANGE / BS)  // 8
#define NKC (D_N / BK)        // 16
#define NTHR 512

// ---- workspace layout (bytes) ----
#define WS_MASSP   0u                                  // Q*C*4 = 4 MB
#define WS_MU      (WS_MASSP + Q_N * C_N * 4u)         // D*4
#define WS_COUNTS  (WS_MU + D_N * 4u)                  // C*4
#define WS_NORMS   (WS_COUNTS + C_N * 4u)              // S*4
#define WS_COLPART (WS_NORMS + S_N * 4u)               // 256*D*4 = 1 MB
#define WS_SUPPB   (WS_COLPART + 256u * D_N * 4u)      // S*D*2 = 32 MB
#define WS_QB      (WS_SUPPB + (unsigned)S_N * D_N * 2u) // Q*D*2 = 8 MB
// total ~45.3 MB

__device__ __forceinline__ u16 f2bf(float f) {
    unsigned x = __float_as_uint(f);
    return (u16)((x + 0x7fffu + ((x >> 16) & 1u)) >> 16);
}

__device__ __forceinline__ float blkSum(float v, float* sh) {
#pragma unroll
    for (int o = 32; o; o >>= 1) v += __shfl_down(v, o);
    if ((threadIdx.x & 63) == 0) sh[threadIdx.x >> 6] = v;
    __syncthreads();
    float r = sh[0] + sh[1] + sh[2] + sh[3];
    __syncthreads();
    return r;
}

__device__ __forceinline__ float blkMax(float v, float* sh) {
#pragma unroll
    for (int o = 32; o; o >>= 1) v = fmaxf(v, __shfl_down(v, o));
    if ((threadIdx.x & 63) == 0) sh[threadIdx.x >> 6] = v;
    __syncthreads();
    float r = fmaxf(fmaxf(sh[0], sh[1]), fmaxf(sh[2], sh[3]));
    __syncthreads();
    return r;
}

// ---- row L2 norms of raw support ----
__global__ void k_norms(const float* __restrict__ sup, float* __restrict__ norms) {
    int lane = threadIdx.x & 63, w = threadIdx.x >> 6;
    int row = blockIdx.x * 4 + w;
    const float4* rp = (const float4*)(sup + (size_t)row * D_N);
    float ss = 0.f;
#pragma unroll
    for (int i = 0; i < 4; i++) {
        float4 v = rp[lane + 64 * i];
        ss += v.x * v.x + v.y * v.y + v.z * v.z + v.w * v.w;
    }
#pragma unroll
    for (int o = 32; o; o >>= 1) ss += __shfl_down(ss, o);
    if (lane == 0) norms[row] = sqrtf(ss);
}

// ---- partial column sums of normalized support (64 rows per block) ----
__global__ void k_colpart(const float* __restrict__ sup, const float* __restrict__ norms,
                          float* __restrict__ colpart) {
    int rc = blockIdx.x >> 2, cg = blockIdx.x & 3;
    int c = cg * 256 + threadIdx.x;
    int r0 = rc * 64;
    float acc = 0.f;
#pragma unroll 4
    for (int i = 0; i < 64; i++) {
        int r = r0 + i;
        float inv = 1.f / fmaxf(norms[r], 1e-8f);
        acc += sup[(size_t)r * D_N + c] * inv;
    }
    colpart[rc * D_N + c] = acc;
}

// ---- reduce partials -> mu ----
__global__ void k_mu(const float* __restrict__ colpart, float* __restrict__ mu) {
    int c = blockIdx.x * 256 + threadIdx.x;
    float s = 0.f;
#pragma unroll 8
    for (int i = 0; i < 256; i++) s += colpart[i * D_N + c];
    mu[c] = s * (1.f / (float)S_N);
}

// ---- support: normalize, center, renormalize, -> bf16 ----
__global__ void k_suptrans(const float* __restrict__ sup, const float* __restrict__ norms,
                           const float* __restrict__ mu, u16* __restrict__ outb) {
    __shared__ float sh[4];
    int r = blockIdx.x, t = threadIdx.x;
    float inv = 1.f / fmaxf(norms[r], 1e-8f);
    float4 x = ((const float4*)(sup + (size_t)r * D_N))[t];
    float4 m = ((const float4*)mu)[t];
    float4 y;
    y.x = x.x * inv - m.x; y.y = x.y * inv - m.y;
    y.z = x.z * inv - m.z; y.w = x.w * inv - m.w;
    float ss = y.x * y.x + y.y * y.y + y.z * y.z + y.w * y.w;
    float tot = blkSum(ss, sh);
    float inv2 = 1.f / fmaxf(sqrtf(tot), 1e-8f);
    ushort4 u;
    u.x = f2bf(y.x * inv2); u.y = f2bf(y.y * inv2);
    u.z = f2bf(y.z * inv2); u.w = f2bf(y.w * inv2);
    ((ushort4*)(outb + (size_t)r * D_N))[t] = u;
}

// ---- query: normalize, center, renormalize, -> bf16 ----
__global__ void k_qtrans(const float* __restrict__ qry, const float* __restrict__ mu,
                         u16* __restrict__ outb) {
    __shared__ float sh[4];
    int r = blockIdx.x, t = threadIdx.x;
    float4 x = ((const float4*)(qry + (size_t)r * D_N))[t];
    float ss1 = x.x * x.x + x.y * x.y + x.z * x.z + x.w * x.w;
    float tot1 = blkSum(ss1, sh);
    float inv1 = 1.f / fmaxf(sqrtf(tot1), 1e-8f);
    float4 m = ((const float4*)mu)[t];
    float4 y;
    y.x = x.x * inv1 - m.x; y.y = x.y * inv1 - m.y;
    y.z = x.z * inv1 - m.z; y.w = x.w * inv1 - m.w;
    float ss2 = y.x * y.x + y.y * y.y + y.z * y.z + y.w * y.w;
    float tot2 = blkSum(ss2, sh);
    float inv2 = 1.f / fmaxf(sqrtf(tot2), 1e-8f);
    ushort4 u;
    u.x = f2bf(y.x * inv2); u.y = f2bf(y.y * inv2);
    u.z = f2bf(y.z * inv2); u.w = f2bf(y.w * inv2);
    ((ushort4*)(outb + (size_t)r * D_N))[t] = u;
}

// ---- label histogram ----
__global__ void k_counts(const int* __restrict__ lab, int* __restrict__ counts) {
    int i = blockIdx.x * 256 + threadIdx.x;
    if (i < S_N) atomicAdd(&counts[lab[i]], 1);
}

// ---- main: sims-GEMM + exp + mass-GEMM against register-synthesized one-hot ----
__launch_bounds__(NTHR, 2)
__global__ void k_mass(const u16* __restrict__ Qb, const u16* __restrict__ Sb,
                       const int* __restrict__ lab, const float* __restrict__ scale_p,
                       float* __restrict__ massp) {
    __shared__ u16 sQ[BQ * BK];       // 16 KB, swizzled
    __shared__ u16 sS[BS * BK];       // 16 KB, swizzled
    __shared__ u16 sP[BQ * BS];       // 32 KB, exp(P) bf16, swizzled
    __shared__ int slabAll[SRANGE];   // 4 KB, all labels for this s-range

    const int t = threadIdx.x;
    const int lane = t & 63, w = t >> 6;
    const int wrow = w >> 1, wcol = w & 1;      // main-GEMM wave grid 4x2
    const int l15 = lane & 15, l4 = lane >> 4;
    const int sblk = blockIdx.x >> 5;           // 0..15  (consecutive bids share s-range -> L2)
    const int qblk = blockIdx.x & 31;           // 0..31
    const int qbase = qblk * BQ;
    const int s0 = sblk * SRANGE;

    const float scale = fminf(fmaxf(*scale_p, 1.f), 20.f);

    // staging: thread t -> 16B chunk at (row = t>>3 [+64], chunk = t&7)
    const int srow = t >> 3, sck = t & 7;
    const int wb0 = (srow * 128 + sck * 16) ^ ((srow & 7) << 4);

    // main fragment read offsets (swizzled)
    int aoff[2][2], boff[4][2];
#pragma unroll
    for (int m = 0; m < 2; m++)
#pragma unroll
        for (int k2 = 0; k2 < 2; k2++) {
            int r = wrow * 32 + m * 16 + l15;
            aoff[m][k2] = (r * 128 + k2 * 64 + l4 * 16) ^ ((r & 7) << 4);
        }
#pragma unroll
    for (int n = 0; n < 4; n++)
#pragma unroll
        for (int k2 = 0; k2 < 2; k2++) {
            int r = wcol * 64 + n * 16 + l15;
            boff[n][k2] = (r * 128 + k2 * 64 + l4 * 16) ^ ((r & 7) << 4);
        }

    uint4 rq[2], rs[2];
    auto loadQ = [&](int kc) {
        const u16* p = Qb + (size_t)(qbase + srow) * D_N + kc * BK + sck * 8;
        rq[0] = *(const uint4*)p;
        rq[1] = *(const uint4*)(p + 64 * D_N);
    };
    auto loadS = [&](int sbase, int kc) {
        const u16* p = Sb + (size_t)(sbase + srow) * D_N + kc * BK + sck * 8;
        rs[0] = *(const uint4*)p;
        rs[1] = *(const uint4*)(p + 64 * D_N);
    };

    for (int i = t; i < SRANGE; i += NTHR) slabAll[i] = lab[s0 + i];
    loadQ(0);
    loadS(s0, 0);

    // mass accumulator: wave covers (h*64 q-rows) x (64 c-cols)
    const int h = w >> 2;
    const int c0 = (w & 3) * 64;
    f32x4 macc[4][4];
#pragma unroll
    for (int m = 0; m < 4; m++)
#pragma unroll
        for (int n = 0; n < 4; n++) macc[m][n] = (f32x4){0.f, 0.f, 0.f, 0.f};

    for (int st = 0; st < NTILES; ++st) {
        const int sbase = s0 + st * BS;
        f32x4 acc[2][4];
#pragma unroll
        for (int m = 0; m < 2; m++)
#pragma unroll
            for (int n = 0; n < 4; n++) acc[m][n] = (f32x4){0.f, 0.f, 0.f, 0.f};

        for (int kc = 0; kc < NKC; ++kc) {
            __syncthreads();  // prior LDS readers done
            *(uint4*)((char*)sQ + wb0) = rq[0];
            *(uint4*)((char*)sQ + wb0 + 8192) = rq[1];
            *(uint4*)((char*)sS + wb0) = rs[0];
            *(uint4*)((char*)sS + wb0 + 8192) = rs[1];
            // T14: issue next chunk's loads; in flight across barrier + MFMA phase
            int nkc = kc + 1, nsb = sbase;
            if (nkc == NKC) { nkc = 0; nsb = (st + 1 < NTILES) ? sbase + BS : sbase; }
            loadQ(nkc);
            loadS(nsb, nkc);
            __syncthreads();

#pragma unroll
            for (int k2 = 0; k2 < 2; k2++) {
                bf16x8 a0 = *(const bf16x8*)((const char*)sQ + aoff[0][k2]);
                bf16x8 a1 = *(const bf16x8*)((const char*)sQ + aoff[1][k2]);
                bf16x8 b0 = *(const bf16x8*)((const char*)sS + boff[0][k2]);
                bf16x8 b1 = *(const bf16x8*)((const char*)sS + boff[1][k2]);
                bf16x8 b2 = *(const bf16x8*)((const char*)sS + boff[2][k2]);
                bf16x8 b3 = *(const bf16x8*)((const char*)sS + boff[3][k2]);
                acc[0][0] = __builtin_amdgcn_mfma_f32_16x16x32_bf16(a0, b0, acc[0][0], 0, 0, 0);
                acc[0][1] = __builtin_amdgcn_mfma_f32_16x16x32_bf16(a0, b1, acc[0][1], 0, 0, 0);
                acc[0][2] = __builtin_amdgcn_mfma_f32_16x16x32_bf16(a0, b2, acc[0][2], 0, 0, 0);
                acc[0][3] = __builtin_amdgcn_mfma_f32_16x16x32_bf16(a0, b3, acc[0][3], 0, 0, 0);
                acc[1][0] = __builtin_amdgcn_mfma_f32_16x16x32_bf16(a1, b0, acc[1][0], 0, 0, 0);
                acc[1][1] = __builtin_amdgcn_mfma_f32_16x16x32_bf16(a1, b1, acc[1][1], 0, 0, 0);
                acc[1][2] = __builtin_amdgcn_mfma_f32_16x16x32_bf16(a1, b2, acc[1][2], 0, 0, 0);
                acc[1][3] = __builtin_amdgcn_mfma_f32_16x16x32_bf16(a1, b3, acc[1][3], 0, 0, 0);
            }
        }

        // ---- exp(P) -> bf16 -> sP (swizzled [q][s], 2B scattered writes) ----
#pragma unroll
        for (int m = 0; m < 2; m++)
#pragma unroll
            for (int n = 0; n < 4; n++) {
                int q = wrow * 32 + m * 16 + l4 * 4;
                int s = wcol * 64 + n * 16 + l15;
#pragma unroll
                for (int r4 = 0; r4 < 4; r4++) {
                    u16 v = f2bf(__expf(acc[m][n][r4] * scale));
                    int qq = q + r4;
                    *(u16*)((char*)sP + (((qq * 256) + s * 2) ^ ((qq & 7) << 4))) = v;
                }
            }
        __syncthreads();  // sP complete

        // ---- mass-GEMM: macc += expP @ onehot(labels); one-hot B synthesized in regs ----
#pragma unroll
        for (int kg = 0; kg < 4; ++kg) {
            int labk[8];
#pragma unroll
            for (int j = 0; j < 8; j++) labk[j] = slabAll[st * BS + kg * 32 + l4 * 8 + j];
            bf16x8 ap[4];
#pragma unroll
            for (int m = 0; m < 4; m++) {
                int r = h * 64 + m * 16 + l15;
                ap[m] = *(const bf16x8*)((const char*)sP +
                                         ((r * 256 + kg * 64 + l4 * 16) ^ ((r & 7) << 4)));
            }
#pragma unroll
            for (int n = 0; n < 4; n++) {
                int c = c0 + n * 16 + l15;
                bf16x8 bo;
#pragma unroll
                for (int j = 0; j < 8; j++) bo[j] = (labk[j] == c) ? (short)0x3F80 : (short)0;
                macc[0][n] = __builtin_amdgcn_mfma_f32_16x16x32_bf16(ap[0], bo, macc[0][n], 0, 0, 0);
                macc[1][n] = __builtin_amdgcn_mfma_f32_16x16x32_bf16(ap[1], bo, macc[1][n], 0, 0, 0);
                macc[2][n] = __builtin_amdgcn_mfma_f32_16x16x32_bf16(ap[2], bo, macc[2][n], 0, 0, 0);
                macc[3][n] = __builtin_amdgcn_mfma_f32_16x16x32_bf16(ap[3], bo, macc[3][n], 0, 0, 0);
            }
        }
        // next tile's loop-top barrier protects sP/slab rewrites
    }

    // ---- flush mass to global (16 adds per cell across the grid) ----
#pragma unroll
    for (int m = 0; m < 4; m++)
#pragma unroll
        for (int n = 0; n < 4; n++) {
            int c = c0 + n * 16 + l15;
#pragma unroll
            for (int r4 = 0; r4 < 4; r4++) {
                int q = qbase + h * 64 + m * 16 + l4 * 4 + r4;
                unsafeAtomicAdd(&massp[(size_t)q * C_N + c], macc[m][n][r4]);
            }
        }
}

// ---- finalize: normalize mass, log, prior, softmax ----
__global__ void k_final(const float* __restrict__ massp, const int* __restrict__ counts,
                        const float* __restrict__ cp_p, float* __restrict__ out) {
    __shared__ float sh[4];
    int q = blockIdx.x, c = threadIdx.x;
    float m = massp[(size_t)q * C_N + c];
    float denom = blkSum(m, sh);
    float cp = *cp_p;
    float logit = logf(fmaxf(m / denom, 1e-8f)) + cp * logf(fmaxf((float)counts[c], 1.f));
    float mx = blkMax(logit, sh);
    float e = __expf(logit - mx);
    float se = blkSum(e, sh);
    out[(size_t)q * C_N + c] = logit;
    out[(size_t)Q_N * C_N + C_N + (size_t)q * C_N + c] = e / se;
    if (q == 0) out[(size_t)Q_N * C_N + c] = (float)c;
}

extern "C" void kernel_launch(void* const* d_in, const int* in_sizes, int n_in,
                              void* d_out, int out_size, void* d_ws, size_t ws_size,
                              hipStream_t stream) {
    const float* sup = (const float*)d_in[0];
    const int* lab = (const int*)d_in[1];
    const float* qry = (const float*)d_in[2];
    const float* ls = (const float*)d_in[3];
    const float* cp = (const float*)d_in[4];
    float* out = (float*)d_out;
    char* ws = (char*)d_ws;

    float* massp = (float*)(ws + WS_MASSP);
    float* mu = (float*)(ws + WS_MU);
    int* counts = (int*)(ws + WS_COUNTS);
    float* norms = (float*)(ws + WS_NORMS);
    float* colpart = (float*)(ws + WS_COLPART);
    u16* suppb = (u16*)(ws + WS_SUPPB);
    u16* qb = (u16*)(ws + WS_QB);

    hipMemsetAsync(massp, 0, Q_N * C_N * sizeof(float), stream);
    hipMemsetAsync(counts, 0, C_N * sizeof(int), stream);
    k_norms<<<S_N / 4, 256, 0, stream>>>(sup, norms);
    k_colpart<<<1024, 256, 0, stream>>>(sup, norms, colpart);
    k_mu<<<D_N / 256, 256, 0, stream>>>(colpart, mu);
    k_suptrans<<<S_N, 256, 0, stream>>>(sup, norms, mu, suppb);
    k_qtrans<<<Q_N, 256, 0, stream>>>(qry, mu, qb);
    k_counts<<<S_N / 256, 256, 0, stream>>>(lab, counts);
    k_mass<<<(Q_N / BQ) * NS, NTHR, 0, stream>>>(qb, suppb, lab, ls, massp);
    k_final<<<Q_N, 256, 0, stream>>>(massp, counts, cp, out);
}

// Round 3
// 578.793 us; speedup vs baseline: 1.8279x; 1.4409x over previous
//
#include <hip/hip_runtime.h>
#include <math.h>

typedef unsigned short u16;
typedef __attribute__((ext_vector_type(8))) short bf16x8;
typedef __attribute__((ext_vector_type(4))) float f32x4;

#define S_N 16384
#define Q_N 4096
#define D_N 1024
#define C_N 256
#define NS 16
#define BQ 128
#define BS 128
#define BK 64
#define SRANGE (S_N / NS)     // 1024
#define NTILES (SRANGE / BS)  // 8
#define NKC (D_N / BK)        // 16
#define NTHR 512

// ---- workspace layout (bytes) ----
#define WS_MASSP   0u                                    // Q*C*4 = 4 MB
#define WS_MU      (WS_MASSP + Q_N * C_N * 4u)           // D*4
#define WS_COUNTS  (WS_MU + D_N * 4u)                    // C*4
#define WS_NORMS   (WS_COUNTS + C_N * 4u)                // S*4
#define WS_COLPART (WS_NORMS + S_N * 4u)                 // 256*D*4 = 1 MB
#define WS_SUPPB   (WS_COLPART + 256u * D_N * 4u)        // S*D*2 = 32 MB
#define WS_QB      (WS_SUPPB + (unsigned)S_N * D_N * 2u) // Q*D*2 = 8 MB

#define GLOAD16(g, l)                                                        \
    __builtin_amdgcn_global_load_lds(                                        \
        (const __attribute__((address_space(1))) void*)(g),                  \
        (__attribute__((address_space(3))) void*)(l), 16, 0, 0)

__device__ __forceinline__ u16 f2bf(float f) {
    unsigned x = __float_as_uint(f);
    return (u16)((x + 0x7fffu + ((x >> 16) & 1u)) >> 16);
}

__device__ __forceinline__ float blkSum(float v, float* sh) {
#pragma unroll
    for (int o = 32; o; o >>= 1) v += __shfl_down(v, o);
    if ((threadIdx.x & 63) == 0) sh[threadIdx.x >> 6] = v;
    __syncthreads();
    float r = sh[0] + sh[1] + sh[2] + sh[3];
    __syncthreads();
    return r;
}

__device__ __forceinline__ float blkMax(float v, float* sh) {
#pragma unroll
    for (int o = 32; o; o >>= 1) v = fmaxf(v, __shfl_down(v, o));
    if ((threadIdx.x & 63) == 0) sh[threadIdx.x >> 6] = v;
    __syncthreads();
    float r = fmaxf(fmaxf(sh[0], sh[1]), fmaxf(sh[2], sh[3]));
    __syncthreads();
    return r;
}

// ---- row L2 norms of raw support ----
__global__ void k_norms(const float* __restrict__ sup, float* __restrict__ norms) {
    int lane = threadIdx.x & 63, w = threadIdx.x >> 6;
    int row = blockIdx.x * 4 + w;
    const float4* rp = (const float4*)(sup + (size_t)row * D_N);
    float ss = 0.f;
#pragma unroll
    for (int i = 0; i < 4; i++) {
        float4 v = rp[lane + 64 * i];
        ss += v.x * v.x + v.y * v.y + v.z * v.z + v.w * v.w;
    }
#pragma unroll
    for (int o = 32; o; o >>= 1) ss += __shfl_down(ss, o);
    if (lane == 0) norms[row] = sqrtf(ss);
}

// ---- partial column sums of normalized support (64 rows per block) ----
__global__ void k_colpart(const float* __restrict__ sup, const float* __restrict__ norms,
                          float* __restrict__ colpart) {
    int rc = blockIdx.x >> 2, cg = blockIdx.x & 3;
    int c = cg * 256 + threadIdx.x;
    int r0 = rc * 64;
    float acc = 0.f;
#pragma unroll 4
    for (int i = 0; i < 64; i++) {
        int r = r0 + i;
        float inv = 1.f / fmaxf(norms[r], 1e-8f);
        acc += sup[(size_t)r * D_N + c] * inv;
    }
    colpart[rc * D_N + c] = acc;
}

// ---- reduce partials -> mu ----
__global__ void k_mu(const float* __restrict__ colpart, float* __restrict__ mu) {
    int c = blockIdx.x * 256 + threadIdx.x;
    float s = 0.f;
#pragma unroll 8
    for (int i = 0; i < 256; i++) s += colpart[i * D_N + c];
    mu[c] = s * (1.f / (float)S_N);
}

// ---- support: normalize, center, renormalize, -> bf16 ----
__global__ void k_suptrans(const float* __restrict__ sup, const float* __restrict__ norms,
                           const float* __restrict__ mu, u16* __restrict__ outb) {
    __shared__ float sh[4];
    int r = blockIdx.x, t = threadIdx.x;
    float inv = 1.f / fmaxf(norms[r], 1e-8f);
    float4 x = ((const float4*)(sup + (size_t)r * D_N))[t];
    float4 m = ((const float4*)mu)[t];
    float4 y;
    y.x = x.x * inv - m.x; y.y = x.y * inv - m.y;
    y.z = x.z * inv - m.z; y.w = x.w * inv - m.w;
    float ss = y.x * y.x + y.y * y.y + y.z * y.z + y.w * y.w;
    float tot = blkSum(ss, sh);
    float inv2 = 1.f / fmaxf(sqrtf(tot), 1e-8f);
    ushort4 u;
    u.x = f2bf(y.x * inv2); u.y = f2bf(y.y * inv2);
    u.z = f2bf(y.z * inv2); u.w = f2bf(y.w * inv2);
    ((ushort4*)(outb + (size_t)r * D_N))[t] = u;
}

// ---- query: normalize, center, renormalize, -> bf16 ----
__global__ void k_qtrans(const float* __restrict__ qry, const float* __restrict__ mu,
                         u16* __restrict__ outb) {
    __shared__ float sh[4];
    int r = blockIdx.x, t = threadIdx.x;
    float4 x = ((const float4*)(qry + (size_t)r * D_N))[t];
    float ss1 = x.x * x.x + x.y * x.y + x.z * x.z + x.w * x.w;
    float tot1 = blkSum(ss1, sh);
    float inv1 = 1.f / fmaxf(sqrtf(tot1), 1e-8f);
    float4 m = ((const float4*)mu)[t];
    float4 y;
    y.x = x.x * inv1 - m.x; y.y = x.y * inv1 - m.y;
    y.z = x.z * inv1 - m.z; y.w = x.w * inv1 - m.w;
    float ss2 = y.x * y.x + y.y * y.y + y.z * y.z + y.w * y.w;
    float tot2 = blkSum(ss2, sh);
    float inv2 = 1.f / fmaxf(sqrtf(tot2), 1e-8f);
    ushort4 u;
    u.x = f2bf(y.x * inv2); u.y = f2bf(y.y * inv2);
    u.z = f2bf(y.z * inv2); u.w = f2bf(y.w * inv2);
    ((ushort4*)(outb + (size_t)r * D_N))[t] = u;
}

// ---- label histogram ----
__global__ void k_counts(const int* __restrict__ lab, int* __restrict__ counts) {
    int i = blockIdx.x * 256 + threadIdx.x;
    if (i < S_N) atomicAdd(&counts[lab[i]], 1);
}

// ---- main: sims-GEMM (gload_lds staged) + exp + mass-GEMM vs reg-synthesized one-hot ----
__launch_bounds__(NTHR, 2)
__global__ void k_mass(const u16* __restrict__ Qb, const u16* __restrict__ Sb,
                       const int* __restrict__ lab, const float* __restrict__ scale_p,
                       float* __restrict__ massp) {
    __shared__ u16 sQ[BQ * BK];       // 16 KB, LINEAR [row][64] (gload_lds dest)
    __shared__ u16 sS[BS * BK];       // 16 KB, LINEAR
    __shared__ u16 sP[BQ * BS];       // 32 KB, exp(P) bf16, swizzled
    __shared__ int slabAll[SRANGE];   // 4 KB

    const int t = threadIdx.x;
    const int lane = t & 63, w = t >> 6;
    const int wrow = w >> 1, wcol = w & 1;      // sims wave grid 4x2
    const int l15 = lane & 15, l4 = lane >> 4;
    const int sblk = blockIdx.x >> 5;
    const int qblk = blockIdx.x & 31;
    const int qbase = qblk * BQ;
    const int s0 = sblk * SRANGE;

    const float scale = fminf(fmaxf(*scale_p, 1.f), 20.f);
    const float sl2 = scale * 1.44269504f;   // fold into exp2

    // staging: thread t <-> 16B at LDS byte t*16 == row-major (t>>3, t&7)
    const int srow = t >> 3, sck = t & 7;
    char* lqb = (char*)sQ + w * 1024;   // wave-uniform LDS base
    char* lsb = (char*)sS + w * 1024;

    // sims fragment read offsets (linear LDS)
    int aoff[2][2], boff[4][2];
#pragma unroll
    for (int m = 0; m < 2; m++)
#pragma unroll
        for (int k2 = 0; k2 < 2; k2++)
            aoff[m][k2] = (wrow * 32 + m * 16 + l15) * 128 + k2 * 64 + l4 * 16;
#pragma unroll
    for (int n = 0; n < 4; n++)
#pragma unroll
        for (int k2 = 0; k2 < 2; k2++)
            boff[n][k2] = (wcol * 64 + n * 16 + l15) * 128 + k2 * 64 + l4 * 16;

    for (int i = t; i < SRANGE; i += NTHR) slabAll[i] = lab[s0 + i];

    // mass accumulator: wave covers (h*64 q-rows) x (64 c-cols)
    const int h = w >> 2;
    const int c0 = (w & 3) * 64;
    f32x4 macc[4][4];
#pragma unroll
    for (int m = 0; m < 4; m++)
#pragma unroll
        for (int n = 0; n < 4; n++) macc[m][n] = (f32x4){0.f, 0.f, 0.f, 0.f};

    for (int st = 0; st < NTILES; ++st) {
        const int sbase = s0 + st * BS;
        f32x4 acc[2][4];
#pragma unroll
        for (int m = 0; m < 2; m++)
#pragma unroll
            for (int n = 0; n < 4; n++) acc[m][n] = (f32x4){0.f, 0.f, 0.f, 0.f};

        for (int kc = 0; kc < NKC; ++kc) {
            // stage this K-chunk direct to LDS (prev readers passed trailing barrier)
            const u16* gq = Qb + (size_t)(qbase + srow) * D_N + kc * BK + sck * 8;
            const u16* gs = Sb + (size_t)(sbase + srow) * D_N + kc * BK + sck * 8;
            GLOAD16(gq, lqb);
            GLOAD16(gq + 64 * D_N, lqb + 8192);
            GLOAD16(gs, lsb);
            GLOAD16(gs + 64 * D_N, lsb + 8192);
            __syncthreads();   // drains vmcnt(0): tiles resident

#pragma unroll
            for (int k2 = 0; k2 < 2; k2++) {
                bf16x8 a0 = *(const bf16x8*)((const char*)sQ + aoff[0][k2]);
                bf16x8 a1 = *(const bf16x8*)((const char*)sQ + aoff[1][k2]);
                bf16x8 b0 = *(const bf16x8*)((const char*)sS + boff[0][k2]);
                bf16x8 b1 = *(const bf16x8*)((const char*)sS + boff[1][k2]);
                bf16x8 b2 = *(const bf16x8*)((const char*)sS + boff[2][k2]);
                bf16x8 b3 = *(const bf16x8*)((const char*)sS + boff[3][k2]);
                acc[0][0] = __builtin_amdgcn_mfma_f32_16x16x32_bf16(a0, b0, acc[0][0], 0, 0, 0);
                acc[0][1] = __builtin_amdgcn_mfma_f32_16x16x32_bf16(a0, b1, acc[0][1], 0, 0, 0);
                acc[0][2] = __builtin_amdgcn_mfma_f32_16x16x32_bf16(a0, b2, acc[0][2], 0, 0, 0);
                acc[0][3] = __builtin_amdgcn_mfma_f32_16x16x32_bf16(a0, b3, acc[0][3], 0, 0, 0);
                acc[1][0] = __builtin_amdgcn_mfma_f32_16x16x32_bf16(a1, b0, acc[1][0], 0, 0, 0);
                acc[1][1] = __builtin_amdgcn_mfma_f32_16x16x32_bf16(a1, b1, acc[1][1], 0, 0, 0);
                acc[1][2] = __builtin_amdgcn_mfma_f32_16x16x32_bf16(a1, b2, acc[1][2], 0, 0, 0);
                acc[1][3] = __builtin_amdgcn_mfma_f32_16x16x32_bf16(a1, b3, acc[1][3], 0, 0, 0);
            }
            __syncthreads();   // readers done before next stage overwrites
        }

        // ---- exp2(P*scale*log2e) -> bf16 -> sP (swizzled [q][s]) ----
#pragma unroll
        for (int m = 0; m < 2; m++)
#pragma unroll
            for (int n = 0; n < 4; n++) {
                int q = wrow * 32 + m * 16 + l4 * 4;
                int s = wcol * 64 + n * 16 + l15;
#pragma unroll
                for (int r4 = 0; r4 < 4; r4++) {
                    u16 v = f2bf(exp2f(acc[m][n][r4] * sl2));
                    int qq = q + r4;
                    *(u16*)((char*)sP + (((qq * 256) + s * 2) ^ ((qq & 7) << 4))) = v;
                }
            }
        __syncthreads();  // sP complete

        // ---- mass-GEMM: macc += expP @ onehot(labels) ----
#pragma unroll
        for (int kg = 0; kg < 4; ++kg) {
            int labk[8];
#pragma unroll
            for (int j = 0; j < 8; j++) labk[j] = slabAll[st * BS + kg * 32 + l4 * 8 + j];
            bf16x8 ap[4];
#pragma unroll
            for (int m = 0; m < 4; m++) {
                int r = h * 64 + m * 16 + l15;
                ap[m] = *(const bf16x8*)((const char*)sP +
                                         ((r * 256 + kg * 64 + l4 * 16) ^ ((r & 7) << 4)));
            }
#pragma unroll
            for (int n = 0; n < 4; n++) {
                int c = c0 + n * 16 + l15;
                bf16x8 bo;
#pragma unroll
                for (int j = 0; j < 8; j++) bo[j] = (labk[j] == c) ? (short)0x3F80 : (short)0;
                macc[0][n] = __builtin_amdgcn_mfma_f32_16x16x32_bf16(ap[0], bo, macc[0][n], 0, 0, 0);
                macc[1][n] = __builtin_amdgcn_mfma_f32_16x16x32_bf16(ap[1], bo, macc[1][n], 0, 0, 0);
                macc[2][n] = __builtin_amdgcn_mfma_f32_16x16x32_bf16(ap[2], bo, macc[2][n], 0, 0, 0);
                macc[3][n] = __builtin_amdgcn_mfma_f32_16x16x32_bf16(ap[3], bo, macc[3][n], 0, 0, 0);
            }
        }
        // next tile's first-stage gload writes sQ/sS (readers long past); sP guarded above
    }

    // ---- flush mass to global (16 adds per cell) ----
#pragma unroll
    for (int m = 0; m < 4; m++)
#pragma unroll
        for (int n = 0; n < 4; n++) {
            int c = c0 + n * 16 + l15;
#pragma unroll
            for (int r4 = 0; r4 < 4; r4++) {
                int q = qbase + h * 64 + m * 16 + l4 * 4 + r4;
                unsafeAtomicAdd(&massp[(size_t)q * C_N + c], macc[m][n][r4]);
            }
        }
}

// ---- finalize: normalize mass, log, prior, softmax ----
__global__ void k_final(const float* __restrict__ massp, const int* __restrict__ counts,
                        const float* __restrict__ cp_p, float* __restrict__ out) {
    __shared__ float sh[4];
    int q = blockIdx.x, c = threadIdx.x;
    float m = massp[(size_t)q * C_N + c];
    float denom = blkSum(m, sh);
    float cp = *cp_p;
    float logit = logf(fmaxf(m / denom, 1e-8f)) + cp * logf(fmaxf((float)counts[c], 1.f));
    float mx = blkMax(logit, sh);
    float e = __expf(logit - mx);
    float se = blkSum(e, sh);
    out[(size_t)q * C_N + c] = logit;
    out[(size_t)Q_N * C_N + C_N + (size_t)q * C_N + c] = e / se;
    if (q == 0) out[(size_t)Q_N * C_N + c] = (float)c;
}

extern "C" void kernel_launch(void* const* d_in, const int* in_sizes, int n_in,
                              void* d_out, int out_size, void* d_ws, size_t ws_size,
                              hipStream_t stream) {
    const float* sup = (const float*)d_in[0];
    const int* lab = (const int*)d_in[1];
    const float* qry = (const float*)d_in[2];
    const float* ls = (const float*)d_in[3];
    const float* cp = (const float*)d_in[4];
    float* out = (float*)d_out;
    char* ws = (char*)d_ws;

    float* massp = (float*)(ws + WS_MASSP);
    float* mu = (float*)(ws + WS_MU);
    int* counts = (int*)(ws + WS_COUNTS);
    float* norms = (float*)(ws + WS_NORMS);
    float* colpart = (float*)(ws + WS_COLPART);
    u16* suppb = (u16*)(ws + WS_SUPPB);
    u16* qb = (u16*)(ws + WS_QB);

    hipMemsetAsync(massp, 0, Q_N * C_N * sizeof(float), stream);
    hipMemsetAsync(counts, 0, C_N * sizeof(int), stream);
    k_norms<<<S_N / 4, 256, 0, stream>>>(sup, norms);
    k_colpart<<<1024, 256, 0, stream>>>(sup, norms, colpart);
    k_mu<<<D_N / 256, 256, 0, stream>>>(colpart, mu);
    k_suptrans<<<S_N, 256, 0, stream>>>(sup, norms, mu, suppb);
    k_qtrans<<<Q_N, 256, 0, stream>>>(qry, mu, qb);
    k_counts<<<S_N / 256, 256, 0, stream>>>(lab, counts);
    k_mass<<<(Q_N / BQ) * NS, NTHR, 0, stream>>>(qb, suppb, lab, ls, massp);
    k_final<<<Q_N, 256, 0, stream>>>(massp, counts, cp, out);
}

// Round 4
// 509.896 us; speedup vs baseline: 2.0748x; 1.1351x over previous
//
#include <hip/hip_runtime.h>
#include <math.h>

typedef unsigned short u16;
typedef __attribute__((ext_vector_type(8))) short bf16x8;
typedef __attribute__((ext_vector_type(4))) float f32x4;

#define S_N 16384
#define Q_N 4096
#define D_N 1024
#define C_N 256
#define NS 16
#define BQ 128
#define BS 128
#define BK 64
#define SRANGE (S_N / NS)     // 1024
#define NTILES (SRANGE / BS)  // 8
#define NKC (D_N / BK)        // 16
#define NTHR 512

// ---- workspace layout (bytes) ----
#define WS_MASSP   0u                                    // Q*C*4 = 4 MB
#define WS_MU      (WS_MASSP + Q_N * C_N * 4u)           // D*4
#define WS_COUNTS  (WS_MU + D_N * 4u)                    // C*4
#define WS_NORMS   (WS_COUNTS + C_N * 4u)                // S*4
#define WS_COLPART (WS_NORMS + S_N * 4u)                 // 256*D*4 = 1 MB
#define WS_SUPPB   (WS_COLPART + 256u * D_N * 4u)        // S*D*2 = 32 MB
#define WS_QB      (WS_SUPPB + (unsigned)S_N * D_N * 2u) // Q*D*2 = 8 MB

#define GLOAD16(g, l)                                                        \
    __builtin_amdgcn_global_load_lds(                                        \
        (const __attribute__((address_space(1))) void*)(g),                  \
        (__attribute__((address_space(3))) void*)(l), 16, 0, 0)

__device__ __forceinline__ u16 f2bf(float f) {
    unsigned x = __float_as_uint(f);
    return (u16)((x + 0x7fffu + ((x >> 16) & 1u)) >> 16);
}

__device__ __forceinline__ float blkSum(float v, float* sh) {
#pragma unroll
    for (int o = 32; o; o >>= 1) v += __shfl_down(v, o);
    if ((threadIdx.x & 63) == 0) sh[threadIdx.x >> 6] = v;
    __syncthreads();
    float r = sh[0] + sh[1] + sh[2] + sh[3];
    __syncthreads();
    return r;
}

__device__ __forceinline__ float blkMax(float v, float* sh) {
#pragma unroll
    for (int o = 32; o; o >>= 1) v = fmaxf(v, __shfl_down(v, o));
    if ((threadIdx.x & 63) == 0) sh[threadIdx.x >> 6] = v;
    __syncthreads();
    float r = fmaxf(fmaxf(sh[0], sh[1]), fmaxf(sh[2], sh[3]));
    __syncthreads();
    return r;
}

// ---- row L2 norms of raw support ----
__global__ void k_norms(const float* __restrict__ sup, float* __restrict__ norms) {
    int lane = threadIdx.x & 63, w = threadIdx.x >> 6;
    int row = blockIdx.x * 4 + w;
    const float4* rp = (const float4*)(sup + (size_t)row * D_N);
    float ss = 0.f;
#pragma unroll
    for (int i = 0; i < 4; i++) {
        float4 v = rp[lane + 64 * i];
        ss += v.x * v.x + v.y * v.y + v.z * v.z + v.w * v.w;
    }
#pragma unroll
    for (int o = 32; o; o >>= 1) ss += __shfl_down(ss, o);
    if (lane == 0) norms[row] = sqrtf(ss);
}

// ---- partial column sums of normalized support (64 rows per block) ----
__global__ void k_colpart(const float* __restrict__ sup, const float* __restrict__ norms,
                          float* __restrict__ colpart) {
    int rc = blockIdx.x >> 2, cg = blockIdx.x & 3;
    int c = cg * 256 + threadIdx.x;
    int r0 = rc * 64;
    float acc = 0.f;
#pragma unroll 4
    for (int i = 0; i < 64; i++) {
        int r = r0 + i;
        float inv = 1.f / fmaxf(norms[r], 1e-8f);
        acc += sup[(size_t)r * D_N + c] * inv;
    }
    colpart[rc * D_N + c] = acc;
}

// ---- reduce partials -> mu ----
__global__ void k_mu(const float* __restrict__ colpart, float* __restrict__ mu) {
    int c = blockIdx.x * 256 + threadIdx.x;
    float s = 0.f;
#pragma unroll 8
    for (int i = 0; i < 256; i++) s += colpart[i * D_N + c];
    mu[c] = s * (1.f / (float)S_N);
}

// ---- support: normalize, center, renormalize, -> bf16 ----
__global__ void k_suptrans(const float* __restrict__ sup, const float* __restrict__ norms,
                           const float* __restrict__ mu, u16* __restrict__ outb) {
    __shared__ float sh[4];
    int r = blockIdx.x, t = threadIdx.x;
    float inv = 1.f / fmaxf(norms[r], 1e-8f);
    float4 x = ((const float4*)(sup + (size_t)r * D_N))[t];
    float4 m = ((const float4*)mu)[t];
    float4 y;
    y.x = x.x * inv - m.x; y.y = x.y * inv - m.y;
    y.z = x.z * inv - m.z; y.w = x.w * inv - m.w;
    float ss = y.x * y.x + y.y * y.y + y.z * y.z + y.w * y.w;
    float tot = blkSum(ss, sh);
    float inv2 = 1.f / fmaxf(sqrtf(tot), 1e-8f);
    ushort4 u;
    u.x = f2bf(y.x * inv2); u.y = f2bf(y.y * inv2);
    u.z = f2bf(y.z * inv2); u.w = f2bf(y.w * inv2);
    ((ushort4*)(outb + (size_t)r * D_N))[t] = u;
}

// ---- query: normalize, center, renormalize, -> bf16 ----
__global__ void k_qtrans(const float* __restrict__ qry, const float* __restrict__ mu,
                         u16* __restrict__ outb) {
    __shared__ float sh[4];
    int r = blockIdx.x, t = threadIdx.x;
    float4 x = ((const float4*)(qry + (size_t)r * D_N))[t];
    float ss1 = x.x * x.x + x.y * x.y + x.z * x.z + x.w * x.w;
    float tot1 = blkSum(ss1, sh);
    float inv1 = 1.f / fmaxf(sqrtf(tot1), 1e-8f);
    float4 m = ((const float4*)mu)[t];
    float4 y;
    y.x = x.x * inv1 - m.x; y.y = x.y * inv1 - m.y;
    y.z = x.z * inv1 - m.z; y.w = x.w * inv1 - m.w;
    float ss2 = y.x * y.x + y.y * y.y + y.z * y.z + y.w * y.w;
    float tot2 = blkSum(ss2, sh);
    float inv2 = 1.f / fmaxf(sqrtf(tot2), 1e-8f);
    ushort4 u;
    u.x = f2bf(y.x * inv2); u.y = f2bf(y.y * inv2);
    u.z = f2bf(y.z * inv2); u.w = f2bf(y.w * inv2);
    ((ushort4*)(outb + (size_t)r * D_N))[t] = u;
}

// ---- label histogram ----
__global__ void k_counts(const int* __restrict__ lab, int* __restrict__ counts) {
    int i = blockIdx.x * 256 + threadIdx.x;
    if (i < S_N) atomicAdd(&counts[lab[i]], 1);
}

// ---- main: pipelined sims-GEMM (gload_lds, dbuf, counted vmcnt) + exp + mass-GEMM ----
__launch_bounds__(NTHR, 2)
__global__ void k_mass(const u16* __restrict__ Qb, const u16* __restrict__ Sb,
                       const int* __restrict__ lab, const float* __restrict__ scale_p,
                       float* __restrict__ massp) {
    __shared__ u16 sQ[2][BQ * BK];    // 2x16 KB, linear-written, content swizzled
    __shared__ u16 sS[2][BS * BK];    // 2x16 KB
    __shared__ u16 sP[BQ * BS];       // 32 KB, exp(P) bf16, swizzled
    __shared__ int slabAll[SRANGE];   // 4 KB

    const int t = threadIdx.x;
    const int lane = t & 63, w = t >> 6;
    const int wrow = w >> 1, wcol = w & 1;      // sims wave grid 4x2
    const int l15 = lane & 15, l4 = lane >> 4;
    const int sblk = blockIdx.x >> 5;
    const int qblk = blockIdx.x & 31;
    const int qbase = qblk * BQ;
    const int s0 = sblk * SRANGE;

    const float scale = fminf(fmaxf(*scale_p, 1.f), 20.f);
    const float sl2 = scale * 1.44269504f;   // fold into exp2

    // staging: thread t stages LDS byte t*16 (linear); global source chunk pre-swizzled
    const int srow = t >> 3;
    const int gck = (t & 7) ^ (srow & 7);    // inverse swizzle on SOURCE (rule 21)
    const int lofs = w * 1024;               // wave-uniform LDS base + lane*16

    // sims fragment read offsets: XOR swizzle within the 128B row
    int aoff[2][2], boff[4][2];
#pragma unroll
    for (int m = 0; m < 2; m++)
#pragma unroll
        for (int k2 = 0; k2 < 2; k2++) {
            int r = wrow * 32 + m * 16 + l15;
            aoff[m][k2] = r * 128 + ((k2 * 64 + l4 * 16) ^ ((r & 7) << 4));
        }
#pragma unroll
    for (int n = 0; n < 4; n++)
#pragma unroll
        for (int k2 = 0; k2 < 2; k2++) {
            int r = wcol * 64 + n * 16 + l15;
            boff[n][k2] = r * 128 + ((k2 * 64 + l4 * 16) ^ ((r & 7) << 4));
        }

    for (int i = t; i < SRANGE; i += NTHR) slabAll[i] = lab[s0 + i];

    auto stage = [&](int sbase, int kc, int buf) {
        const u16* gq = Qb + (size_t)(qbase + srow) * D_N + kc * BK + gck * 8;
        const u16* gs = Sb + (size_t)(sbase + srow) * D_N + kc * BK + gck * 8;
        char* lq = (char*)sQ[buf] + lofs;
        char* ls = (char*)sS[buf] + lofs;
        GLOAD16(gq, lq);
        GLOAD16(gq + 64 * D_N, lq + 8192);
        GLOAD16(gs, ls);
        GLOAD16(gs + 64 * D_N, ls + 8192);
    };

    // mass accumulator: wave covers (h*64 q-rows) x (64 c-cols)
    const int h = w >> 2;
    const int c0 = (w & 3) * 64;
    f32x4 macc[4][4];
#pragma unroll
    for (int m = 0; m < 4; m++)
#pragma unroll
        for (int n = 0; n < 4; n++) macc[m][n] = (f32x4){0.f, 0.f, 0.f, 0.f};

    stage(s0, 0, 0);   // prologue: chunk 0 -> buf 0

    for (int st = 0; st < NTILES; ++st) {
        const int sbase = s0 + st * BS;
        f32x4 acc[2][4];
#pragma unroll
        for (int m = 0; m < 2; m++)
#pragma unroll
            for (int n = 0; n < 4; n++) acc[m][n] = (f32x4){0.f, 0.f, 0.f, 0.f};

        for (int kc = 0; kc < NKC; ++kc) {
            const int buf = kc & 1;
            // issue next chunk's loads -> other buffer (stays in flight across MFMA)
            int nkc = kc + 1, nsb = sbase;
            if (nkc == NKC) { nkc = 0; nsb = (st + 1 < NTILES) ? sbase + BS : sbase; }
            stage(nsb, nkc, buf ^ 1);
            asm volatile("s_waitcnt vmcnt(4)" ::: "memory");  // current chunk resident
            __builtin_amdgcn_s_barrier();                     // no vmcnt drain
            __builtin_amdgcn_sched_barrier(0);

            const char* bq = (const char*)sQ[buf];
            const char* bs = (const char*)sS[buf];
            __builtin_amdgcn_s_setprio(1);
#pragma unroll
            for (int k2 = 0; k2 < 2; k2++) {
                bf16x8 a0 = *(const bf16x8*)(bq + aoff[0][k2]);
                bf16x8 a1 = *(const bf16x8*)(bq + aoff[1][k2]);
                bf16x8 b0 = *(const bf16x8*)(bs + boff[0][k2]);
                bf16x8 b1 = *(const bf16x8*)(bs + boff[1][k2]);
                bf16x8 b2 = *(const bf16x8*)(bs + boff[2][k2]);
                bf16x8 b3 = *(const bf16x8*)(bs + boff[3][k2]);
                acc[0][0] = __builtin_amdgcn_mfma_f32_16x16x32_bf16(a0, b0, acc[0][0], 0, 0, 0);
                acc[0][1] = __builtin_amdgcn_mfma_f32_16x16x32_bf16(a0, b1, acc[0][1], 0, 0, 0);
                acc[0][2] = __builtin_amdgcn_mfma_f32_16x16x32_bf16(a0, b2, acc[0][2], 0, 0, 0);
                acc[0][3] = __builtin_amdgcn_mfma_f32_16x16x32_bf16(a0, b3, acc[0][3], 0, 0, 0);
                acc[1][0] = __builtin_amdgcn_mfma_f32_16x16x32_bf16(a1, b0, acc[1][0], 0, 0, 0);
                acc[1][1] = __builtin_amdgcn_mfma_f32_16x16x32_bf16(a1, b1, acc[1][1], 0, 0, 0);
                acc[1][2] = __builtin_amdgcn_mfma_f32_16x16x32_bf16(a1, b2, acc[1][2], 0, 0, 0);
                acc[1][3] = __builtin_amdgcn_mfma_f32_16x16x32_bf16(a1, b3, acc[1][3], 0, 0, 0);
            }
            __builtin_amdgcn_s_setprio(0);
            __builtin_amdgcn_sched_barrier(0);
            __builtin_amdgcn_s_barrier();   // readers done; buf becomes next prefetch target
        }

        // ---- exp2(P*scale*log2e) -> bf16 -> sP (swizzled [q][s]) ----
#pragma unroll
        for (int m = 0; m < 2; m++)
#pragma unroll
            for (int n = 0; n < 4; n++) {
                int q = wrow * 32 + m * 16 + l4 * 4;
                int s = wcol * 64 + n * 16 + l15;
#pragma unroll
                for (int r4 = 0; r4 < 4; r4++) {
                    u16 v = f2bf(exp2f(acc[m][n][r4] * sl2));
                    int qq = q + r4;
                    *(u16*)((char*)sP + (((qq * 256) + s * 2) ^ ((qq & 7) << 4))) = v;
                }
            }
        // sP ready; keep next-tile prefetch in flight (no vmcnt drain)
        asm volatile("s_waitcnt lgkmcnt(0)" ::: "memory");
        __builtin_amdgcn_sched_barrier(0);
        __builtin_amdgcn_s_barrier();

        // ---- mass-GEMM: macc += expP @ onehot(labels) ----
#pragma unroll
        for (int kg = 0; kg < 4; ++kg) {
            int labk[8];
#pragma unroll
            for (int j = 0; j < 8; j++) labk[j] = slabAll[st * BS + kg * 32 + l4 * 8 + j];
            bf16x8 ap[4];
#pragma unroll
            for (int m = 0; m < 4; m++) {
                int r = h * 64 + m * 16 + l15;
                ap[m] = *(const bf16x8*)((const char*)sP +
                                         ((r * 256 + kg * 64 + l4 * 16) ^ ((r & 7) << 4)));
            }
#pragma unroll
            for (int n = 0; n < 4; n++) {
                int c = c0 + n * 16 + l15;
                bf16x8 bo;
#pragma unroll
                for (int j = 0; j < 8; j++) bo[j] = (labk[j] == c) ? (short)0x3F80 : (short)0;
                macc[0][n] = __builtin_amdgcn_mfma_f32_16x16x32_bf16(ap[0], bo, macc[0][n], 0, 0, 0);
                macc[1][n] = __builtin_amdgcn_mfma_f32_16x16x32_bf16(ap[1], bo, macc[1][n], 0, 0, 0);
                macc[2][n] = __builtin_amdgcn_mfma_f32_16x16x32_bf16(ap[2], bo, macc[2][n], 0, 0, 0);
                macc[3][n] = __builtin_amdgcn_mfma_f32_16x16x32_bf16(ap[3], bo, macc[3][n], 0, 0, 0);
            }
        }
        // sP rewritten only after next tile's kc loop (>=32 barriers away) -> safe
    }

    // ---- flush mass to global (16 adds per cell) ----
#pragma unroll
    for (int m = 0; m < 4; m++)
#pragma unroll
        for (int n = 0; n < 4; n++) {
            int c = c0 + n * 16 + l15;
#pragma unroll
            for (int r4 = 0; r4 < 4; r4++) {
                int q = qbase + h * 64 + m * 16 + l4 * 4 + r4;
                unsafeAtomicAdd(&massp[(size_t)q * C_N + c], macc[m][n][r4]);
            }
        }
}

// ---- finalize: normalize mass, log, prior, softmax ----
__global__ void k_final(const float* __restrict__ massp, const int* __restrict__ counts,
                        const float* __restrict__ cp_p, float* __restrict__ out) {
    __shared__ float sh[4];
    int q = blockIdx.x, c = threadIdx.x;
    float m = massp[(size_t)q * C_N + c];
    float denom = blkSum(m, sh);
    float cp = *cp_p;
    float logit = logf(fmaxf(m / denom, 1e-8f)) + cp * logf(fmaxf((float)counts[c], 1.f));
    float mx = blkMax(logit, sh);
    float e = __expf(logit - mx);
    float se = blkSum(e, sh);
    out[(size_t)q * C_N + c] = logit;
    out[(size_t)Q_N * C_N + C_N + (size_t)q * C_N + c] = e / se;
    if (q == 0) out[(size_t)Q_N * C_N + c] = (float)c;
}

extern "C" void kernel_launch(void* const* d_in, const int* in_sizes, int n_in,
                              void* d_out, int out_size, void* d_ws, size_t ws_size,
                              hipStream_t stream) {
    const float* sup = (const float*)d_in[0];
    const int* lab = (const int*)d_in[1];
    const float* qry = (const float*)d_in[2];
    const float* ls = (const float*)d_in[3];
    const float* cp = (const float*)d_in[4];
    float* out = (float*)d_out;
    char* ws = (char*)d_ws;

    float* massp = (float*)(ws + WS_MASSP);
    float* mu = (float*)(ws + WS_MU);
    int* counts = (int*)(ws + WS_COUNTS);
    float* norms = (float*)(ws + WS_NORMS);
    float* colpart = (float*)(ws + WS_COLPART);
    u16* suppb = (u16*)(ws + WS_SUPPB);
    u16* qb = (u16*)(ws + WS_QB);

    hipMemsetAsync(massp, 0, Q_N * C_N * sizeof(float), stream);
    hipMemsetAsync(counts, 0, C_N * sizeof(int), stream);
    k_norms<<<S_N / 4, 256, 0, stream>>>(sup, norms);
    k_colpart<<<1024, 256, 0, stream>>>(sup, norms, colpart);
    k_mu<<<D_N / 256, 256, 0, stream>>>(colpart, mu);
    k_suptrans<<<S_N, 256, 0, stream>>>(sup, norms, mu, suppb);
    k_qtrans<<<Q_N, 256, 0, stream>>>(qry, mu, qb);
    k_counts<<<S_N / 256, 256, 0, stream>>>(lab, counts);
    k_mass<<<(Q_N / BQ) * NS, NTHR, 0, stream>>>(qb, suppb, lab, ls, massp);
    k_final<<<Q_N, 256, 0, stream>>>(massp, counts, cp, out);
}